// Round 6
// baseline (629.778 us; speedup 1.0000x reference)
//
#include <hip/hip_runtime.h>

// Problem constants (N=64, D=64, H=64, W=64, K=512)
#define VQ_D   64
#define VQ_K   512
#define VQ_HW  4096
#define VQ_M   262144
#define VQ_LOSS_OFF 16777216
#define VQ_IDX_OFF  16777217

// Ambiguity margin: worst-case |approx-rank - ref-rank| per k is < 5e-5
// (bf16 hi/lo split residue + MFMA fp32 accumulation-order slack + the
// reference's two fp32 roundings at magnitude zsq~64..150); a ranking flip
// needs 2x that. 2.5e-4 gives >2.5x safety margin; rescue rate ~4%.
#define VQ_EPS  2.5e-4f

typedef float  f32x4  __attribute__((ext_vector_type(4)));
typedef short  bf16x8 __attribute__((ext_vector_type(8)));

__device__ __forceinline__ unsigned short f2bf_rne(float f) {
    unsigned u = __float_as_uint(f);
    u += 0x7FFFu + ((u >> 16) & 1u);
    return (unsigned short)(u >> 16);
}
__device__ __forceinline__ float bf2f(unsigned short h) {
    return __uint_as_float(((unsigned)h) << 16);
}

// ---------------------------------------------------------------------------
// Kernel 1: e_sq[k] = sum_d emb[k][d]^2, replicating numpy's pairwise sum
// (n=64 path). Workspace use: 2048 B only (proven safe in passing rounds).
// ---------------------------------------------------------------------------
__global__ void vq_prep(const float* __restrict__ emb, float* __restrict__ esq) {
#pragma clang fp contract(off)
    int k = blockIdx.x * 256 + threadIdx.x;
    if (k < VQ_K) {
        const float* e = emb + k * VQ_D;
        float p[VQ_D];
#pragma unroll
        for (int d = 0; d < VQ_D; ++d) p[d] = e[d] * e[d];
        float r[8];
#pragma unroll
        for (int j = 0; j < 8; ++j) r[j] = p[j];
#pragma unroll
        for (int i = 8; i < VQ_D; i += 8)
#pragma unroll
            for (int j = 0; j < 8; ++j) r[j] += p[i + j];
        esq[k] = ((r[0] + r[1]) + (r[2] + r[3])) + ((r[4] + r[5]) + (r[6] + r[7]));
    }
}

// ---------------------------------------------------------------------------
// Kernel 2: MFMA main. Block = 256 thr = 4 waves; wave owns 64 points
// (4 m-subtiles of 16). Codebook bf16 hi/lo split is done IN-KERNEL while
// staging to LDS (no workspace dependence). Distances via 3-product MFMA
// (zh*eh + zl*eh + zh*el, 16x16x32 bf16). Ranking value v_k = esq_k - 2*acc
// (zsq shifts all k equally). Per point track (best, second, idx); if the
// gap < EPS the exact argmin is ambiguous under the proven error bound ->
// wave-cooperative exact rescan with the bitwise reference path.
// ---------------------------------------------------------------------------
__global__ __launch_bounds__(256, 2) void vq_main(
        const float* __restrict__ z_e,
        const float* __restrict__ emb,
        const float* __restrict__ esq,
        float* __restrict__ out,
        double* __restrict__ loss_acc)
{
#pragma clang fp contract(off)
    __shared__ __align__(16) short lbh[2048 * 8];   // 32 KB: one phase, hi
    __shared__ __align__(16) short lbl[2048 * 8];   // 32 KB: one phase, lo
    __shared__ float lesq[512];
    __shared__ float wsum[4];

    const int tid  = threadIdx.x;
    const int wave = tid >> 6, lane = tid & 63;
    const int c15  = lane & 15, g = lane >> 4;

    lesq[tid]       = esq[tid];
    lesq[tid + 256] = esq[tid + 256];

    const int mblk = blockIdx.x * 256;               // block's first point
    const int n    = mblk >> 12;                     // all 256 pts in one n
    const int hwb  = (mblk & 4095) + wave * 64;      // wave's first hw
    const float* zn = z_e + (size_t)n * 262144;

    // ---- A fragments: z hi/lo for 4 m-subtiles x 2 k-halves ----
    bf16x8 ah[4][2], al[4][2];
#pragma unroll
    for (int ms = 0; ms < 4; ++ms) {
        const int hw = hwb + ms * 16 + c15;
#pragma unroll
        for (int s = 0; s < 2; ++s) {
#pragma unroll
            for (int e = 0; e < 8; ++e) {
                const int d = 32 * s + 8 * g + e;
                float f = zn[(size_t)d * 4096 + hw];
                unsigned short h = f2bf_rne(f);
                ah[ms][s][e] = (short)h;
                al[ms][s][e] = (short)f2bf_rne(f - bf2f(h));
            }
        }
    }

    float best[4][4], sec[4][4];
    int   bidx[4][4];
#pragma unroll
    for (int ms = 0; ms < 4; ++ms)
#pragma unroll
        for (int r = 0; r < 4; ++r) {
            best[ms][r] = 3.4e38f; sec[ms][r] = 3.4e38f; bidx[ms][r] = 0;
        }

    // ---- scan K in two LDS phases of 256 rows ----
    for (int ph = 0; ph < 2; ++ph) {
        __syncthreads();                             // prior readers done
        // stage + split: 2048 float8 chunks, 8 per thread, coalesced loads.
        // slot(tl,s,gg,cc) = (tl*2+s)*64 + gg*16 + cc holds
        // e[ph*256 + 16*tl + cc][32*s + 8*gg .. +7] as bf16 hi/lo.
#pragma unroll
        for (int j = 0; j < 8; ++j) {
            const int f8  = j * 256 + tid;           // 0..2047
            const int row = f8 >> 3;                 // local row 0..255
            const int ch  = f8 & 7;                  // 8-float chunk
            const float* src = emb + ((ph * 256 + row) * 64 + ch * 8);
            float x[8];
            *(f32x4*)&x[0] = *(const f32x4*)(src);
            *(f32x4*)&x[4] = *(const f32x4*)(src + 4);
            bf16x8 vh, vl;
#pragma unroll
            for (int e = 0; e < 8; ++e) {
                unsigned short h = f2bf_rne(x[e]);
                vh[e] = (short)h;
                vl[e] = (short)f2bf_rne(x[e] - bf2f(h));
            }
            const int s  = ch >> 2, gg = ch & 3;
            const int tl = row >> 4, cc = row & 15;
            const int slot = (tl * 2 + s) * 64 + gg * 16 + cc;
            *(bf16x8*)&lbh[slot * 8] = vh;
            *(bf16x8*)&lbl[slot * 8] = vl;
        }
        __syncthreads();

        for (int tl = 0; tl < 16; ++tl) {
            const int tg = ph * 16 + tl;
            const bf16x8 bh0 = *(const bf16x8*)&lbh[((tl * 2 + 0) * 64 + lane) * 8];
            const bf16x8 bh1 = *(const bf16x8*)&lbh[((tl * 2 + 1) * 64 + lane) * 8];
            const bf16x8 bl0 = *(const bf16x8*)&lbl[((tl * 2 + 0) * 64 + lane) * 8];
            const bf16x8 bl1 = *(const bf16x8*)&lbl[((tl * 2 + 1) * 64 + lane) * 8];

            f32x4 acc[4];
#pragma unroll
            for (int ms = 0; ms < 4; ++ms) acc[ms] = (f32x4){0.f, 0.f, 0.f, 0.f};
#pragma unroll
            for (int ms = 0; ms < 4; ++ms) {
                acc[ms] = __builtin_amdgcn_mfma_f32_16x16x32_bf16(ah[ms][0], bh0, acc[ms], 0, 0, 0);
                acc[ms] = __builtin_amdgcn_mfma_f32_16x16x32_bf16(ah[ms][1], bh1, acc[ms], 0, 0, 0);
                acc[ms] = __builtin_amdgcn_mfma_f32_16x16x32_bf16(al[ms][0], bh0, acc[ms], 0, 0, 0);
                acc[ms] = __builtin_amdgcn_mfma_f32_16x16x32_bf16(al[ms][1], bh1, acc[ms], 0, 0, 0);
                acc[ms] = __builtin_amdgcn_mfma_f32_16x16x32_bf16(ah[ms][0], bl0, acc[ms], 0, 0, 0);
                acc[ms] = __builtin_amdgcn_mfma_f32_16x16x32_bf16(ah[ms][1], bl1, acc[ms], 0, 0, 0);
            }

            const float ev = lesq[tg * 16 + c15];
            const int   k  = tg * 16 + c15;
#pragma unroll
            for (int ms = 0; ms < 4; ++ms)
#pragma unroll
                for (int r = 0; r < 4; ++r) {
                    float v = __builtin_fmaf(-2.f, acc[ms][r], ev);
                    bool lt = v < best[ms][r];
                    sec[ms][r]  = lt ? best[ms][r] : fminf(sec[ms][r], v);
                    best[ms][r] = lt ? v : best[ms][r];
                    bidx[ms][r] = lt ? k : bidx[ms][r];
                }
        }
    }

    // ---- butterfly-merge (best,second,idx) across the 16 cols ----
#pragma unroll
    for (int ms = 0; ms < 4; ++ms)
#pragma unroll
        for (int r = 0; r < 4; ++r) {
            float b = best[ms][r], s2 = sec[ms][r]; int bi = bidx[ms][r];
#pragma unroll
            for (int off = 1; off <= 8; off <<= 1) {
                float ob = __shfl_xor(b,  off, 64);
                float os = __shfl_xor(s2, off, 64);
                int   oi = __shfl_xor(bi, off, 64);
                bool lt = ob < b;
                float loser = lt ? b : ob;
                s2 = fminf(fminf(s2, os), loser);
                b  = lt ? ob : b;
                bi = lt ? oi : bi;
            }
            best[ms][r] = b; sec[ms][r] = s2; bidx[ms][r] = bi;
        }

    // ---- ownership gather: lane p owns point p = ms*16 + 4*g' + r' ----
    const int srcl = 16 * ((lane & 15) >> 2);
    float bb_ = 3.4e38f, ss_ = 3.4e38f; int ii_ = 0;
#pragma unroll
    for (int ms = 0; ms < 4; ++ms)
#pragma unroll
        for (int r = 0; r < 4; ++r) {
            float gb = __shfl(best[ms][r], srcl, 64);
            float gs = __shfl(sec[ms][r],  srcl, 64);
            int   gi = __shfl(bidx[ms][r], srcl, 64);
            bool hit = (ms == (lane >> 4)) && (r == (lane & 3));
            bb_ = hit ? gb : bb_; ss_ = hit ? gs : ss_; ii_ = hit ? gi : ii_;
        }

    // ---- ambiguous points: wave-cooperative EXACT rescan (bitwise path) ----
    unsigned long long msk = __ballot(ss_ - bb_ < VQ_EPS);
    while (msk) {
        const int j = __ffsll(msk) - 1;
        msk &= msk - 1;
        const float* zr = zn + hwb + j;              // wave-uniform point
        float zf[VQ_D];
#pragma unroll
        for (int d = 0; d < VQ_D; ++d) zf[d] = zr[(size_t)d * 4096];
        float r8[8];
#pragma unroll
        for (int dj = 0; dj < 8; ++dj) r8[dj] = zf[dj] * zf[dj];
#pragma unroll
        for (int i = 8; i < VQ_D; i += 8)
#pragma unroll
            for (int dj = 0; dj < 8; ++dj) r8[dj] += zf[i + dj] * zf[i + dj];
        const float zsq = ((r8[0] + r8[1]) + (r8[2] + r8[3]))
                        + ((r8[4] + r8[5]) + (r8[6] + r8[7]));
        float fb = 3.4e38f; int fk = 0;
#pragma unroll
        for (int q = 0; q < 8; ++q) {                // 8 rows/lane, k ascending
            const int kk = lane + 64 * q;
            const float* er = emb + kk * VQ_D;
            float aq = 0.f;
#pragma unroll
            for (int c4 = 0; c4 < 16; ++c4) {
                f32x4 e4 = *(const f32x4*)(er + c4 * 4);
#pragma unroll
                for (int x = 0; x < 4; ++x)
                    aq = __builtin_fmaf(zf[c4 * 4 + x], e4[x], aq);
            }
            float tt = zsq + lesq[kk];
            float dd = tt - 2.0f * aq;
            if (dd < fb) { fb = dd; fk = kk; }       // strict <: first occurrence
        }
#pragma unroll
        for (int off = 32; off > 0; off >>= 1) {     // lexicographic (dist, k)
            float ob = __shfl_xor(fb, off, 64);
            int   ok = __shfl_xor(fk, off, 64);
            if (ob < fb || (ob == fb && ok < fk)) { fb = ob; fk = ok; }
        }
        if (lane == j) ii_ = fk;
    }

    // ---- epilogue: gather row, write z_q + idx, accumulate loss ----
    const int m_own = mblk + wave * 64 + lane;
    const int hwp   = hwb + lane;
    const float* zp = zn + hwp;
    const float* eb = emb + ii_ * VQ_D;
    float* op = out + (size_t)n * 262144 + hwp;
    float lsum = 0.f;
#pragma unroll
    for (int d = 0; d < VQ_D; ++d) {
        float q = eb[d];
        op[(size_t)d * 4096] = q;                    // coalesced across lanes
        float diff = zp[(size_t)d * 4096] - q;
        lsum = __builtin_fmaf(diff, diff, lsum);
    }
    out[VQ_IDX_OFF + m_own] = (float)ii_;

    for (int off = 32; off > 0; off >>= 1)
        lsum += __shfl_down(lsum, off, 64);
    if (lane == 0) wsum[wave] = lsum;
    __syncthreads();
    if (tid == 0) {
        float b = wsum[0] + wsum[1] + wsum[2] + wsum[3];
        atomicAdd(loss_acc, (double)b);
    }
}

// ---------------------------------------------------------------------------
// Kernel 3: finalize loss (mean over M*D = 16777216 elements).
// ---------------------------------------------------------------------------
__global__ void vq_fin(const double* __restrict__ loss_acc, float* __restrict__ out) {
    if (threadIdx.x == 0)
        out[VQ_LOSS_OFF] = (float)(*loss_acc / 16777216.0);
}

extern "C" void kernel_launch(void* const* d_in, const int* in_sizes, int n_in,
                              void* d_out, int out_size, void* d_ws, size_t ws_size,
                              hipStream_t stream) {
    const float* z_e = (const float*)d_in[0];
    const float* emb = (const float*)d_in[1];
    float* out = (float*)d_out;

    // ws layout: [0,8) double loss accumulator, [8, 8+2048) float esq[512]
    double* loss_acc = (double*)d_ws;
    float*  esq      = (float*)((char*)d_ws + 8);

    (void)hipMemsetAsync(d_ws, 0, 8, stream);
    vq_prep<<<2, 256, 0, stream>>>(emb, esq);
    vq_main<<<VQ_M / 256, 256, 0, stream>>>(z_e, emb, esq, out, loss_acc);
    vq_fin<<<1, 64, 0, stream>>>(loss_acc, out);
}

// Round 7
// 359.963 us; speedup vs baseline: 1.7496x; 1.7496x over previous
//
#include <hip/hip_runtime.h>

// Problem constants (N=64, D=64, H=64, W=64, K=512)
#define VQ_D   64
#define VQ_K   512
#define VQ_HW  4096
#define VQ_M   262144
#define VQ_LOSS_OFF 16777216
#define VQ_IDX_OFF  16777217

// Ambiguity margin: provable per-pair ranking-flip bound is ~2e-5
// (ref's two fp32 roundings at magnitude zsq~64..150: 2x8e-6, + approx
// error: MFMA fp32 accumulation-order slack ~1.5e-6 + dropped zl*el
// term ~1e-7, doubled for the pair). 1e-4 = 5x safety margin; expected
// rescue rate ~1.7% of points (~1 per wave).
#define VQ_EPS  1e-4f

typedef float  f32x4  __attribute__((ext_vector_type(4)));
typedef short  bf16x8 __attribute__((ext_vector_type(8)));

__device__ __forceinline__ unsigned short f2bf_rne(float f) {
    unsigned u = __float_as_uint(f);
    u += 0x7FFFu + ((u >> 16) & 1u);
    return (unsigned short)(u >> 16);
}
__device__ __forceinline__ float bf2f(unsigned short h) {
    return __uint_as_float(((unsigned)h) << 16);
}
// LDS fragment-slot byte offset with bank swizzle. Involution applied on
// BOTH write and read. Kills the 8-way write conflict (8 lanes at 256B
// stride -> same banks) by folding slot bits 4-5 (gg) into byte bits 4-5;
// read side (slot = t2*64 + lane) stays a bijective in-window lane
// permutation -> still conflict-free.
__device__ __forceinline__ int ldx(int slot) {
    return (slot << 4) ^ (((slot >> 4) & 3) << 4);
}

// ---------------------------------------------------------------------------
// Kernel 1: e_sq[k] = sum_d emb[k][d]^2, replicating numpy's pairwise sum
// (n=64 path). Workspace use: 2056 B only.
// ---------------------------------------------------------------------------
__global__ void vq_prep(const float* __restrict__ emb, float* __restrict__ esq) {
#pragma clang fp contract(off)
    int k = blockIdx.x * 256 + threadIdx.x;
    if (k < VQ_K) {
        const float* e = emb + k * VQ_D;
        float p[VQ_D];
#pragma unroll
        for (int d = 0; d < VQ_D; ++d) p[d] = e[d] * e[d];
        float r[8];
#pragma unroll
        for (int j = 0; j < 8; ++j) r[j] = p[j];
#pragma unroll
        for (int i = 8; i < VQ_D; i += 8)
#pragma unroll
            for (int j = 0; j < 8; ++j) r[j] += p[i + j];
        esq[k] = ((r[0] + r[1]) + (r[2] + r[3])) + ((r[4] + r[5]) + (r[6] + r[7]));
    }
}

// ---------------------------------------------------------------------------
// Kernel 2: MFMA main. Block = 256 thr = 4 waves; wave owns 64 points
// (4 m-subtiles of 16). Codebook bf16 hi/lo split in-kernel during LDS
// staging (swizzled slots). Distances via 3-product MFMA (zh*eh + zl*eh +
// zh*el, 16x16x32 bf16); ranking value v_k = esq_k - 2*acc. Track
// (best, second, idx) per point; gap < EPS -> wave-cooperative exact
// rescan with the bitwise reference path (register-lean, streaming).
// ---------------------------------------------------------------------------
__global__ __launch_bounds__(256, 2) void vq_main(
        const float* __restrict__ z_e,
        const float* __restrict__ emb,
        const float* __restrict__ esq,
        float* __restrict__ out,
        double* __restrict__ loss_acc)
{
#pragma clang fp contract(off)
    __shared__ __align__(16) char lbh[32768];   // one phase, hi (swizzled)
    __shared__ __align__(16) char lbl[32768];   // one phase, lo (swizzled)
    __shared__ float lesq[512];
    __shared__ float wsum[4];

    const int tid  = threadIdx.x;
    const int wave = tid >> 6, lane = tid & 63;
    const int c15  = lane & 15, g = lane >> 4;

    lesq[tid]       = esq[tid];
    lesq[tid + 256] = esq[tid + 256];

    const int mblk = blockIdx.x * 256;               // block's first point
    const int n    = mblk >> 12;                     // all 256 pts in one n
    const int hwb  = (mblk & 4095) + wave * 64;      // wave's first hw
    const float* zn = z_e + (size_t)n * 262144;

    // ---- A fragments: z hi/lo for 4 m-subtiles x 2 k-halves ----
    bf16x8 ah[4][2], al[4][2];
#pragma unroll
    for (int ms = 0; ms < 4; ++ms) {
        const int hw = hwb + ms * 16 + c15;
#pragma unroll
        for (int s = 0; s < 2; ++s) {
#pragma unroll
            for (int e = 0; e < 8; ++e) {
                const int d = 32 * s + 8 * g + e;
                float f = zn[(size_t)d * 4096 + hw];
                unsigned short h = f2bf_rne(f);
                ah[ms][s][e] = (short)h;
                al[ms][s][e] = (short)f2bf_rne(f - bf2f(h));
            }
        }
    }

    float best[4][4], sec[4][4];
    int   bidx[4][4];
#pragma unroll
    for (int ms = 0; ms < 4; ++ms)
#pragma unroll
        for (int r = 0; r < 4; ++r) {
            best[ms][r] = 3.4e38f; sec[ms][r] = 3.4e38f; bidx[ms][r] = 0;
        }

    // ---- scan K in two LDS phases of 256 rows ----
    for (int ph = 0; ph < 2; ++ph) {
        __syncthreads();                             // prior readers done
        // stage + split: 2048 float8 chunks, 8/thread, coalesced loads.
        // slot(tl,s,gg,cc) = (tl*2+s)*64 + gg*16 + cc holds
        // e[ph*256 + 16*tl + cc][32*s + 8*gg .. +7] as bf16 hi/lo.
#pragma unroll
        for (int j = 0; j < 8; ++j) {
            const int f8  = j * 256 + tid;           // 0..2047
            const int row = f8 >> 3;                 // local row 0..255
            const int ch  = f8 & 7;                  // 8-float chunk
            const float* src = emb + ((ph * 256 + row) * 64 + ch * 8);
            float x[8];
            *(f32x4*)&x[0] = *(const f32x4*)(src);
            *(f32x4*)&x[4] = *(const f32x4*)(src + 4);
            bf16x8 vh, vl;
#pragma unroll
            for (int e = 0; e < 8; ++e) {
                unsigned short h = f2bf_rne(x[e]);
                vh[e] = (short)h;
                vl[e] = (short)f2bf_rne(x[e] - bf2f(h));
            }
            const int s  = ch >> 2, gg = ch & 3;
            const int tl = row >> 4, cc = row & 15;
            const int slot = (tl * 2 + s) * 64 + gg * 16 + cc;
            *(bf16x8*)(lbh + ldx(slot)) = vh;
            *(bf16x8*)(lbl + ldx(slot)) = vl;
        }
        __syncthreads();

        for (int tl = 0; tl < 16; ++tl) {
            const int tg = ph * 16 + tl;
            const bf16x8 bh0 = *(const bf16x8*)(lbh + ldx((tl * 2 + 0) * 64 + lane));
            const bf16x8 bh1 = *(const bf16x8*)(lbh + ldx((tl * 2 + 1) * 64 + lane));
            const bf16x8 bl0 = *(const bf16x8*)(lbl + ldx((tl * 2 + 0) * 64 + lane));
            const bf16x8 bl1 = *(const bf16x8*)(lbl + ldx((tl * 2 + 1) * 64 + lane));

            f32x4 acc[4];
#pragma unroll
            for (int ms = 0; ms < 4; ++ms) acc[ms] = (f32x4){0.f, 0.f, 0.f, 0.f};
#pragma unroll
            for (int ms = 0; ms < 4; ++ms) {
                acc[ms] = __builtin_amdgcn_mfma_f32_16x16x32_bf16(ah[ms][0], bh0, acc[ms], 0, 0, 0);
                acc[ms] = __builtin_amdgcn_mfma_f32_16x16x32_bf16(ah[ms][1], bh1, acc[ms], 0, 0, 0);
                acc[ms] = __builtin_amdgcn_mfma_f32_16x16x32_bf16(al[ms][0], bh0, acc[ms], 0, 0, 0);
                acc[ms] = __builtin_amdgcn_mfma_f32_16x16x32_bf16(al[ms][1], bh1, acc[ms], 0, 0, 0);
                acc[ms] = __builtin_amdgcn_mfma_f32_16x16x32_bf16(ah[ms][0], bl0, acc[ms], 0, 0, 0);
                acc[ms] = __builtin_amdgcn_mfma_f32_16x16x32_bf16(ah[ms][1], bl1, acc[ms], 0, 0, 0);
            }

            const float ev = lesq[tg * 16 + c15];
            const int   k  = tg * 16 + c15;
#pragma unroll
            for (int ms = 0; ms < 4; ++ms)
#pragma unroll
                for (int r = 0; r < 4; ++r) {
                    float v = __builtin_fmaf(-2.f, acc[ms][r], ev);
                    bool lt = v < best[ms][r];
                    sec[ms][r]  = lt ? best[ms][r] : fminf(sec[ms][r], v);
                    best[ms][r] = lt ? v : best[ms][r];
                    bidx[ms][r] = lt ? k : bidx[ms][r];
                }
        }
    }

    // ---- butterfly-merge (best,second,idx) across the 16 cols ----
#pragma unroll
    for (int ms = 0; ms < 4; ++ms)
#pragma unroll
        for (int r = 0; r < 4; ++r) {
            float b = best[ms][r], s2 = sec[ms][r]; int bi = bidx[ms][r];
#pragma unroll
            for (int off = 1; off <= 8; off <<= 1) {
                float ob = __shfl_xor(b,  off, 64);
                float os = __shfl_xor(s2, off, 64);
                int   oi = __shfl_xor(bi, off, 64);
                bool lt = ob < b;
                float loser = lt ? b : ob;
                s2 = fminf(fminf(s2, os), loser);
                b  = lt ? ob : b;
                bi = lt ? oi : bi;
            }
            best[ms][r] = b; sec[ms][r] = s2; bidx[ms][r] = bi;
        }

    // ---- ownership gather: lane p owns point p (ms=p>>4, prow=p&15) ----
    const int srcl = 16 * ((lane & 15) >> 2);
    float bb_ = 3.4e38f, ss_ = 3.4e38f; int ii_ = 0;
#pragma unroll
    for (int ms = 0; ms < 4; ++ms)
#pragma unroll
        for (int r = 0; r < 4; ++r) {
            float gb = __shfl(best[ms][r], srcl, 64);
            float gs = __shfl(sec[ms][r],  srcl, 64);
            int   gi = __shfl(bidx[ms][r], srcl, 64);
            bool hit = (ms == (lane >> 4)) && (r == (lane & 3));
            bb_ = hit ? gb : bb_; ss_ = hit ? gs : ss_; ii_ = hit ? gi : ii_;
        }

    // ---- ambiguous points: wave-cooperative EXACT rescan, register-lean.
    //      Lane handles rows [8*lane, 8*lane+8) -> gathered lines fully
    //      consumed. Bitwise reference path; lexicographic (dist,k) wins. ----
    unsigned long long msk = __ballot(ss_ - bb_ < VQ_EPS);
    while (msk) {
        const int j = __ffsll(msk) - 1;
        msk &= msk - 1;
        const float* zr = zn + hwb + j;              // wave-uniform point
        // zsq: numpy pairwise (streaming, 8 regs)
        float r8[8];
#pragma unroll
        for (int dj = 0; dj < 8; ++dj) {
            float f = zr[(size_t)dj * 4096];
            r8[dj] = f * f;
        }
#pragma unroll
        for (int i = 8; i < 64; i += 8)
#pragma unroll
            for (int dj = 0; dj < 8; ++dj) {
                float f = zr[(size_t)(i + dj) * 4096];
                r8[dj] += f * f;
            }
        const float zsq = ((r8[0] + r8[1]) + (r8[2] + r8[3]))
                        + ((r8[4] + r8[5]) + (r8[6] + r8[7]));
        // dots: 8 contiguous rows per lane, sequential fma chains (d asc.)
        float a[8];
#pragma unroll
        for (int q = 0; q < 8; ++q) a[q] = 0.f;
        const float* er0 = emb + (size_t)(lane * 8) * VQ_D;
        for (int c4 = 0; c4 < 16; ++c4) {
            f32x4 z4;
#pragma unroll
            for (int x = 0; x < 4; ++x) z4[x] = zr[(size_t)(c4 * 4 + x) * 4096];
#pragma unroll
            for (int q = 0; q < 8; ++q) {
                f32x4 e4 = *(const f32x4*)(er0 + q * VQ_D + c4 * 4);
#pragma unroll
                for (int x = 0; x < 4; ++x)
                    a[q] = __builtin_fmaf(z4[x], e4[x], a[q]);
            }
        }
        float fb = 3.4e38f; int fk = 0;
#pragma unroll
        for (int q = 0; q < 8; ++q) {                // k ascending within lane
            const int kk = lane * 8 + q;
            float tt = zsq + lesq[kk];
            float dd = tt - 2.0f * a[q];
            if (dd < fb) { fb = dd; fk = kk; }       // strict <: first occurrence
        }
#pragma unroll
        for (int off = 32; off > 0; off >>= 1) {     // lexicographic (dist, k)
            float ob = __shfl_xor(fb, off, 64);
            int   ok = __shfl_xor(fk, off, 64);
            if (ob < fb || (ob == fb && ok < fk)) { fb = ob; fk = ok; }
        }
        if (lane == j) ii_ = fk;
    }

    // ---- epilogue: gather row, write z_q + idx, accumulate loss ----
    const int m_own = mblk + wave * 64 + lane;
    const int hwp   = hwb + lane;
    const float* zp = zn + hwp;
    const float* eb = emb + ii_ * VQ_D;
    float* op = out + (size_t)n * 262144 + hwp;
    float lsum = 0.f;
#pragma unroll
    for (int d = 0; d < VQ_D; ++d) {
        float q = eb[d];
        op[(size_t)d * 4096] = q;                    // coalesced across lanes
        float diff = zp[(size_t)d * 4096] - q;
        lsum = __builtin_fmaf(diff, diff, lsum);
    }
    out[VQ_IDX_OFF + m_own] = (float)ii_;

    for (int off = 32; off > 0; off >>= 1)
        lsum += __shfl_down(lsum, off, 64);
    if (lane == 0) wsum[wave] = lsum;
    __syncthreads();
    if (tid == 0) {
        float b = wsum[0] + wsum[1] + wsum[2] + wsum[3];
        atomicAdd(loss_acc, (double)b);
    }
}

// ---------------------------------------------------------------------------
// Kernel 3: finalize loss (mean over M*D = 16777216 elements).
// ---------------------------------------------------------------------------
__global__ void vq_fin(const double* __restrict__ loss_acc, float* __restrict__ out) {
    if (threadIdx.x == 0)
        out[VQ_LOSS_OFF] = (float)(*loss_acc / 16777216.0);
}

extern "C" void kernel_launch(void* const* d_in, const int* in_sizes, int n_in,
                              void* d_out, int out_size, void* d_ws, size_t ws_size,
                              hipStream_t stream) {
    const float* z_e = (const float*)d_in[0];
    const float* emb = (const float*)d_in[1];
    float* out = (float*)d_out;

    // ws layout: [0,8) double loss accumulator, [8, 8+2048) float esq[512]
    double* loss_acc = (double*)d_ws;
    float*  esq      = (float*)((char*)d_ws + 8);

    (void)hipMemsetAsync(d_ws, 0, 8, stream);
    vq_prep<<<2, 256, 0, stream>>>(emb, esq);
    vq_main<<<VQ_M / 256, 256, 0, stream>>>(z_e, emb, esq, out, loss_acc);
    vq_fin<<<1, 64, 0, stream>>>(loss_acc, out);
}

// Round 9
// 309.826 us; speedup vs baseline: 2.0327x; 1.1618x over previous
//
#include <hip/hip_runtime.h>

// Problem constants (N=64, D=64, H=64, W=64, K=512)
#define VQ_D   64
#define VQ_K   512
#define VQ_HW  4096
#define VQ_M   262144
#define VQ_LOSS_OFF 16777216
#define VQ_IDX_OFF  16777217

// Ambiguity margin: provable per-pair ranking-flip bound ~2e-5; 1e-4 = 5x
// safety. Rescue rate ~1.7% of points (mean gap ~6e-3). Exact-rescue path
// reproduces the reference bitwise, so EPS only affects speed, not output.
#define VQ_EPS  1e-4f

typedef float  f32x4  __attribute__((ext_vector_type(4)));
typedef short  bf16x8 __attribute__((ext_vector_type(8)));

__device__ __forceinline__ unsigned short f2bf_rne(float f) {
    unsigned u = __float_as_uint(f);
    u += 0x7FFFu + ((u >> 16) & 1u);
    return (unsigned short)(u >> 16);
}
__device__ __forceinline__ float bf2f(unsigned short h) {
    return __uint_as_float(((unsigned)h) << 16);
}
// LDS fragment-slot byte offset with bank swizzle (involution on write+read).
__device__ __forceinline__ int ldx(int slot) {
    return (slot << 4) ^ (((slot >> 4) & 3) << 4);
}

// ---------------------------------------------------------------------------
// Kernel 1: e_sq[k] = sum_d emb[k][d]^2 (numpy pairwise, n=64 path).
// ---------------------------------------------------------------------------
__global__ void vq_prep(const float* __restrict__ emb, float* __restrict__ esq) {
#pragma clang fp contract(off)
    int k = blockIdx.x * 256 + threadIdx.x;
    if (k < VQ_K) {
        const float* e = emb + k * VQ_D;
        float p[VQ_D];
#pragma unroll
        for (int d = 0; d < VQ_D; ++d) p[d] = e[d] * e[d];
        float r[8];
#pragma unroll
        for (int j = 0; j < 8; ++j) r[j] = p[j];
#pragma unroll
        for (int i = 8; i < VQ_D; i += 8)
#pragma unroll
            for (int j = 0; j < 8; ++j) r[j] += p[i + j];
        esq[k] = ((r[0] + r[1]) + (r[2] + r[3])) + ((r[4] + r[5]) + (r[6] + r[7]));
    }
}

// ---------------------------------------------------------------------------
// Kernel 2: MFMA argmin (indices only). Block = 256 thr = 4 waves; wave owns
// 32 points (2 m-subtiles). 4 LDS phases x 128 rows (34 KB -> 4 blocks/CU,
// 16 waves/CU). B-fragments register-double-buffered one k-tile ahead;
// 12 MFMAs interleaved ms-major. Gap < EPS -> wave-cooperative exact rescan
// (bitwise reference path). Writes idx only; epilogue is a separate kernel.
// ---------------------------------------------------------------------------
__global__ __launch_bounds__(256, 4) void vq_main(
        const float* __restrict__ z_e,
        const float* __restrict__ emb,
        const float* __restrict__ esq,
        float* __restrict__ out)
{
#pragma clang fp contract(off)
    __shared__ __align__(16) char lbh[16384];   // one phase (128 rows), hi
    __shared__ __align__(16) char lbl[16384];   // one phase, lo
    __shared__ float lesq[512];

    const int tid  = threadIdx.x;
    const int wave = tid >> 6, lane = tid & 63;
    const int c15  = lane & 15, g = lane >> 4;

    lesq[tid]       = esq[tid];
    lesq[tid + 256] = esq[tid + 256];

    const int mblk = blockIdx.x * 128;               // block's first point
    const int n    = mblk >> 12;                     // all 128 pts in one n
    const int hwb  = (mblk & 4095) + wave * 32;      // wave's first hw
    const float* zn = z_e + (size_t)n * 262144;

    // ---- A fragments: z hi/lo for 2 m-subtiles x 2 k-halves ----
    bf16x8 ah[2][2], al[2][2];
#pragma unroll
    for (int ms = 0; ms < 2; ++ms) {
        const int hw = hwb + ms * 16 + c15;
#pragma unroll
        for (int s = 0; s < 2; ++s) {
#pragma unroll
            for (int e = 0; e < 8; ++e) {
                const int d = 32 * s + 8 * g + e;
                float f = zn[(size_t)d * 4096 + hw];
                unsigned short h = f2bf_rne(f);
                ah[ms][s][e] = (short)h;
                al[ms][s][e] = (short)f2bf_rne(f - bf2f(h));
            }
        }
    }

    float best[2][4], sec[2][4];
    int   bidx[2][4];
#pragma unroll
    for (int ms = 0; ms < 2; ++ms)
#pragma unroll
        for (int r = 0; r < 4; ++r) {
            best[ms][r] = 3.4e38f; sec[ms][r] = 3.4e38f; bidx[ms][r] = 0;
        }

    // ---- scan K in four LDS phases of 128 rows ----
    for (int ph = 0; ph < 4; ++ph) {
        __syncthreads();                             // prior readers done
        // stage + split: 1024 float8 chunks, 4/thread, coalesced loads.
        // slot(tl,s,gg,cc) = (tl*2+s)*64 + gg*16 + cc holds
        // e[ph*128 + 16*tl + cc][32*s + 8*gg .. +7] as bf16 hi/lo.
#pragma unroll
        for (int j = 0; j < 4; ++j) {
            const int f8  = j * 256 + tid;           // 0..1023
            const int row = f8 >> 3;                 // local row 0..127
            const int ch  = f8 & 7;                  // 8-float chunk
            const float* src = emb + ((ph * 128 + row) * 64 + ch * 8);
            float x[8];
            *(f32x4*)&x[0] = *(const f32x4*)(src);
            *(f32x4*)&x[4] = *(const f32x4*)(src + 4);
            bf16x8 vh, vl;
#pragma unroll
            for (int e = 0; e < 8; ++e) {
                unsigned short h = f2bf_rne(x[e]);
                vh[e] = (short)h;
                vl[e] = (short)f2bf_rne(x[e] - bf2f(h));
            }
            const int s  = ch >> 2, gg = ch & 3;
            const int tl = row >> 4, cc = row & 15;
            const int slot = (tl * 2 + s) * 64 + gg * 16 + cc;
            *(bf16x8*)(lbh + ldx(slot)) = vh;
            *(bf16x8*)(lbl + ldx(slot)) = vl;
        }
        __syncthreads();

        // 8 k-tiles, register-double-buffered one tile ahead
        bf16x8 cbh0 = *(const bf16x8*)(lbh + ldx(0 * 64 + lane));
        bf16x8 cbh1 = *(const bf16x8*)(lbh + ldx(1 * 64 + lane));
        bf16x8 cbl0 = *(const bf16x8*)(lbl + ldx(0 * 64 + lane));
        bf16x8 cbl1 = *(const bf16x8*)(lbl + ldx(1 * 64 + lane));
#pragma unroll
        for (int tl = 0; tl < 8; ++tl) {
            bf16x8 nbh0, nbh1, nbl0, nbl1;
            if (tl < 7) {
                nbh0 = *(const bf16x8*)(lbh + ldx((tl * 2 + 2) * 64 + lane));
                nbh1 = *(const bf16x8*)(lbh + ldx((tl * 2 + 3) * 64 + lane));
                nbl0 = *(const bf16x8*)(lbl + ldx((tl * 2 + 2) * 64 + lane));
                nbl1 = *(const bf16x8*)(lbl + ldx((tl * 2 + 3) * 64 + lane));
            }
            f32x4 acc0 = {0.f, 0.f, 0.f, 0.f};
            f32x4 acc1 = {0.f, 0.f, 0.f, 0.f};
            acc0 = __builtin_amdgcn_mfma_f32_16x16x32_bf16(ah[0][0], cbh0, acc0, 0, 0, 0);
            acc1 = __builtin_amdgcn_mfma_f32_16x16x32_bf16(ah[1][0], cbh0, acc1, 0, 0, 0);
            acc0 = __builtin_amdgcn_mfma_f32_16x16x32_bf16(ah[0][1], cbh1, acc0, 0, 0, 0);
            acc1 = __builtin_amdgcn_mfma_f32_16x16x32_bf16(ah[1][1], cbh1, acc1, 0, 0, 0);
            acc0 = __builtin_amdgcn_mfma_f32_16x16x32_bf16(al[0][0], cbh0, acc0, 0, 0, 0);
            acc1 = __builtin_amdgcn_mfma_f32_16x16x32_bf16(al[1][0], cbh0, acc1, 0, 0, 0);
            acc0 = __builtin_amdgcn_mfma_f32_16x16x32_bf16(al[0][1], cbh1, acc0, 0, 0, 0);
            acc1 = __builtin_amdgcn_mfma_f32_16x16x32_bf16(al[1][1], cbh1, acc1, 0, 0, 0);
            acc0 = __builtin_amdgcn_mfma_f32_16x16x32_bf16(ah[0][0], cbl0, acc0, 0, 0, 0);
            acc1 = __builtin_amdgcn_mfma_f32_16x16x32_bf16(ah[1][0], cbl0, acc1, 0, 0, 0);
            acc0 = __builtin_amdgcn_mfma_f32_16x16x32_bf16(ah[0][1], cbl1, acc0, 0, 0, 0);
            acc1 = __builtin_amdgcn_mfma_f32_16x16x32_bf16(ah[1][1], cbl1, acc1, 0, 0, 0);

            const int tg = ph * 8 + tl;
            const float ev = lesq[tg * 16 + c15];
            const int   k  = tg * 16 + c15;
#pragma unroll
            for (int r = 0; r < 4; ++r) {
                float v0 = __builtin_fmaf(-2.f, acc0[r], ev);
                bool lt0 = v0 < best[0][r];
                sec[0][r]  = lt0 ? best[0][r] : fminf(sec[0][r], v0);
                best[0][r] = lt0 ? v0 : best[0][r];
                bidx[0][r] = lt0 ? k : bidx[0][r];
                float v1 = __builtin_fmaf(-2.f, acc1[r], ev);
                bool lt1 = v1 < best[1][r];
                sec[1][r]  = lt1 ? best[1][r] : fminf(sec[1][r], v1);
                best[1][r] = lt1 ? v1 : best[1][r];
                bidx[1][r] = lt1 ? k : bidx[1][r];
            }
            cbh0 = nbh0; cbh1 = nbh1; cbl0 = nbl0; cbl1 = nbl1;
        }
    }

    // ---- butterfly-merge (best,second,idx) across the 16 cols ----
#pragma unroll
    for (int ms = 0; ms < 2; ++ms)
#pragma unroll
        for (int r = 0; r < 4; ++r) {
            float b = best[ms][r], s2 = sec[ms][r]; int bi = bidx[ms][r];
#pragma unroll
            for (int off = 1; off <= 8; off <<= 1) {
                float ob = __shfl_xor(b,  off, 64);
                float os = __shfl_xor(s2, off, 64);
                int   oi = __shfl_xor(bi, off, 64);
                bool lt = ob < b;
                float loser = lt ? b : ob;
                s2 = fminf(fminf(s2, os), loser);
                b  = lt ? ob : b;
                bi = lt ? oi : bi;
            }
            best[ms][r] = b; sec[ms][r] = s2; bidx[ms][r] = bi;
        }

    // ---- ownership: lane p (<32) owns point p = ms*16 + 4g'+r' ----
    const int srcl = 16 * ((lane & 15) >> 2);
    float bb_ = 3.4e38f, ss_ = 3.4e38f; int ii_ = 0;
#pragma unroll
    for (int ms = 0; ms < 2; ++ms)
#pragma unroll
        for (int r = 0; r < 4; ++r) {
            float gb = __shfl(best[ms][r], srcl, 64);
            float gs = __shfl(sec[ms][r],  srcl, 64);
            int   gi = __shfl(bidx[ms][r], srcl, 64);
            bool hit = (ms == (lane >> 4)) && (r == (lane & 3));
            bb_ = hit ? gb : bb_; ss_ = hit ? gs : ss_; ii_ = hit ? gi : ii_;
        }
    const bool own = lane < 32;

    // ---- ambiguous points: wave-cooperative EXACT rescan (bitwise path) ----
    unsigned long long msk = __ballot(own && (ss_ - bb_ < VQ_EPS));
    while (msk) {
        const int j = __ffsll(msk) - 1;
        msk &= msk - 1;
        const float* zr = zn + hwb + j;              // wave-uniform point
        float r8[8];
#pragma unroll
        for (int dj = 0; dj < 8; ++dj) {
            float f = zr[(size_t)dj * 4096];
            r8[dj] = f * f;
        }
#pragma unroll
        for (int i = 8; i < 64; i += 8)
#pragma unroll
            for (int dj = 0; dj < 8; ++dj) {
                float f = zr[(size_t)(i + dj) * 4096];
                r8[dj] += f * f;
            }
        const float zsq = ((r8[0] + r8[1]) + (r8[2] + r8[3]))
                        + ((r8[4] + r8[5]) + (r8[6] + r8[7]));
        float a[8];
#pragma unroll
        for (int q = 0; q < 8; ++q) a[q] = 0.f;
        const float* er0 = emb + (size_t)(lane * 8) * VQ_D;
        for (int c4 = 0; c4 < 16; ++c4) {
            f32x4 z4;
#pragma unroll
            for (int x = 0; x < 4; ++x) z4[x] = zr[(size_t)(c4 * 4 + x) * 4096];
#pragma unroll
            for (int q = 0; q < 8; ++q) {
                f32x4 e4 = *(const f32x4*)(er0 + q * VQ_D + c4 * 4);
#pragma unroll
                for (int x = 0; x < 4; ++x)
                    a[q] = __builtin_fmaf(z4[x], e4[x], a[q]);
            }
        }
        float fb = 3.4e38f; int fk = 0;
#pragma unroll
        for (int q = 0; q < 8; ++q) {                // k ascending within lane
            const int kk = lane * 8 + q;
            float tt = zsq + lesq[kk];
            float dd = tt - 2.0f * a[q];
            if (dd < fb) { fb = dd; fk = kk; }       // strict <: first occurrence
        }
#pragma unroll
        for (int off = 32; off > 0; off >>= 1) {     // lexicographic (dist, k)
            float ob = __shfl_xor(fb, off, 64);
            int   ok = __shfl_xor(fk, off, 64);
            if (ob < fb || (ob == fb && ok < fk)) { fb = ob; fk = ok; }
        }
        if (lane == j) ii_ = fk;
    }

    // ---- write indices (epilogue is a separate high-occupancy kernel) ----
    if (own)
        out[VQ_IDX_OFF + mblk + wave * 32 + lane] = (float)ii_;
}

// ---------------------------------------------------------------------------
// Kernel 2b: epilogue. 1 thread/point, no LDS pressure -> high occupancy so
// the per-lane codebook-row gather latency pipelines across many waves.
// Same per-point arithmetic and per-block (256-pt) loss grouping as the
// previously passing kernel.
// ---------------------------------------------------------------------------
__global__ __launch_bounds__(256, 8) void vq_epi(
        const float* __restrict__ z_e,
        const float* __restrict__ emb,
        float* __restrict__ out,
        double* __restrict__ loss_acc)
{
#pragma clang fp contract(off)
    __shared__ float wsum[4];
    const int tid  = threadIdx.x;
    const int wave = tid >> 6, lane = tid & 63;
    const int m    = blockIdx.x * 256 + tid;
    const int n    = m >> 12;
    const int hw   = m & 4095;

    const float* zp = z_e + (size_t)n * 262144 + hw;
    const int ii = (int)out[VQ_IDX_OFF + m];
    const float* eb = emb + (size_t)ii * VQ_D;
    float* op = out + (size_t)n * 262144 + hw;

    float lsum = 0.f;
#pragma unroll
    for (int c4 = 0; c4 < 16; ++c4) {
        f32x4 e4 = *(const f32x4*)(eb + c4 * 4);     // row gather, L1-resident
#pragma unroll
        for (int x = 0; x < 4; ++x) {
            const int d = c4 * 4 + x;
            float q = e4[x];
            op[(size_t)d * 4096] = q;                // coalesced across lanes
            float diff = zp[(size_t)d * 4096] - q;
            lsum = __builtin_fmaf(diff, diff, lsum);
        }
    }

    for (int off = 32; off > 0; off >>= 1)
        lsum += __shfl_down(lsum, off, 64);
    if (lane == 0) wsum[wave] = lsum;
    __syncthreads();
    if (tid == 0) {
        float b = wsum[0] + wsum[1] + wsum[2] + wsum[3];
        atomicAdd(loss_acc, (double)b);
    }
}

// ---------------------------------------------------------------------------
// Kernel 3: finalize loss (mean over M*D = 16777216 elements).
// ---------------------------------------------------------------------------
__global__ void vq_fin(const double* __restrict__ loss_acc, float* __restrict__ out) {
    if (threadIdx.x == 0)
        out[VQ_LOSS_OFF] = (float)(*loss_acc / 16777216.0);
}

extern "C" void kernel_launch(void* const* d_in, const int* in_sizes, int n_in,
                              void* d_out, int out_size, void* d_ws, size_t ws_size,
                              hipStream_t stream) {
    const float* z_e = (const float*)d_in[0];
    const float* emb = (const float*)d_in[1];
    float* out = (float*)d_out;

    // ws layout: [0,8) double loss accumulator, [8, 8+2048) float esq[512]
    double* loss_acc = (double*)d_ws;
    float*  esq      = (float*)((char*)d_ws + 8);

    (void)hipMemsetAsync(d_ws, 0, 8, stream);
    vq_prep<<<2, 256, 0, stream>>>(emb, esq);
    vq_main<<<VQ_M / 128, 256, 0, stream>>>(z_e, emb, esq, out);
    vq_epi<<<VQ_M / 256, 256, 0, stream>>>(z_e, emb, out, loss_acc);
    vq_fin<<<1, 64, 0, stream>>>(loss_acc, out);
}